// Round 8
// baseline (109.746 us; speedup 1.0000x reference)
//
#include <hip/hip_runtime.h>
#include <hip/hip_bf16.h>
#include <cstdint>

// GAT fused layer: B=4, N=2048, F=128, H=8, HD=16, all fp32 I/O.
// Identity: exp(leaky(si+sj)) = max(exp(si)exp(sj), exp(.2si)exp(.2sj))
//   -> inner loop per 2 nodes: 2x v_pk_mul_f32 + 1x v_pk_max_f32, no
//   transcendentals. Mask: row-major u64 bitmasks, per-node bit extract
//   (round-4-proven). NO inline asm (round 6/7 lessons).
// prep: blocks [0,1024) proj (XW -> WxT bf16 + EI {exp,exp5} float2 +
//   EjT/Ej5T deinterleaved), block 1024 WoT, [1025,3073) row-major pack.
// gat: 512 blocks x 16 waves (8 heads x 2 j-halves); register
//   double-buffered j-loop; aggregation + row-sum via
//   mfma_f32_16x16x32_bf16 (B=ones); LDS pair-combine; fused out-proj+ELU.

typedef float f32x2 __attribute__((ext_vector_type(2)));
typedef float f32x4 __attribute__((ext_vector_type(4)));
typedef __bf16 bf16x8 __attribute__((ext_vector_type(8)));

__global__ __launch_bounds__(256)
void prep_kernel(const float* __restrict__ x, const float* __restrict__ W,
                 const float* __restrict__ a, const float* __restrict__ Wo,
                 const int* __restrict__ adj,
                 unsigned short* __restrict__ wxT,
                 float2* __restrict__ EI,
                 float* __restrict__ EjT, float* __restrict__ Ej5T,
                 float* __restrict__ WoT,
                 unsigned long long* __restrict__ bits)
{
    const int t = threadIdx.x;

    if (blockIdx.x >= 1025) {
        // ---- row-major pack: 2048 blocks x 4 rows (round-4-proven)
        const int wid = (blockIdx.x - 1025) * 4 + (t >> 6);  // row 0..8191
        const int lane = t & 63;
        const int* row = adj + (size_t)wid * 2048;
        unsigned long long* brow = bits + (size_t)wid * 32;
        #pragma unroll 2
        for (int it = 0; it < 8; ++it) {
            const int base = it * 256;
            const unsigned long long w0 = __ballot(row[base + lane] != 0);
            const unsigned long long w1 = __ballot(row[base + 64 + lane] != 0);
            const unsigned long long w2 = __ballot(row[base + 128 + lane] != 0);
            const unsigned long long w3 = __ballot(row[base + 192 + lane] != 0);
            if (lane == 0) {
                ulonglong2 p0; p0.x = w0; p0.y = w1;
                ulonglong2 p1; p1.x = w2; p1.y = w3;
                *reinterpret_cast<ulonglong2*>(&brow[it * 4])     = p0;
                *reinterpret_cast<ulonglong2*>(&brow[it * 4 + 2]) = p1;
            }
        }
        return;
    }

    // ---- proj: blocks 0..1024 (t<128 active)
    const int blk = blockIdx.x;
    if (blk == 1024) {
        if (t < 128)
            for (int k = 0; k < 128; ++k)
                WoT[k * 128 + t] = Wo[t * 128 + k];
        return;
    }
    __shared__ float xl[8 * 128];
    __shared__ float xw[8 * 128];
    const int row0 = blk * 8;
    if (t < 128) {
        #pragma unroll
        for (int r = 0; r < 8; ++r)
            xl[r * 128 + t] = x[(size_t)(row0 + r) * 128 + t];
    }
    __syncthreads();

    if (t < 128) {
        float acc[8] = {0.f, 0.f, 0.f, 0.f, 0.f, 0.f, 0.f, 0.f};
        for (int k = 0; k < 128; k += 4) {
            const float w0 = W[(k + 0) * 128 + t];
            const float w1 = W[(k + 1) * 128 + t];
            const float w2 = W[(k + 2) * 128 + t];
            const float w3 = W[(k + 3) * 128 + t];
            #pragma unroll
            for (int r = 0; r < 8; ++r) {
                const float4 xv = *reinterpret_cast<const float4*>(&xl[r * 128 + k]);
                acc[r] += xv.x * w0 + xv.y * w1 + xv.z * w2 + xv.w * w3;
            }
        }
        #pragma unroll
        for (int r = 0; r < 8; ++r) xw[r * 128 + t] = acc[r];
    }
    __syncthreads();

    if (t < 128) {
        const int b = row0 >> 11, n0 = row0 & 2047;
        bf16x8 st;
        #pragma unroll
        for (int r = 0; r < 8; ++r) st[r] = (__bf16)xw[r * 128 + t];
        *reinterpret_cast<bf16x8*>(&wxT[((size_t)(b * 128 + t)) * 2048 + n0]) = st;

        const int r = t >> 4, h = (t >> 1) & 7, s = t & 1;
        float dot = 0.f;
        #pragma unroll
        for (int d = 0; d < 16; ++d)
            dot += xw[r * 128 + h * 16 + d] * a[h * 32 + s * 16 + d];
        const float ef  = __expf(dot);
        const float ef5 = __expf(0.2f * dot);
        const int idx = (b * 8 + h) * 2048 + n0 + r;
        if (s) { EjT[idx] = ef; Ej5T[idx] = ef5; }
        else   { float2 ev; ev.x = ef; ev.y = ef5; EI[idx] = ev; }
    }
}

__global__ __launch_bounds__(1024, 4)
void gat_kernel(const unsigned long long* __restrict__ bits,
                const unsigned short* __restrict__ wxT,
                const float2* __restrict__ EI,
                const float* __restrict__ EjT, const float* __restrict__ Ej5T,
                const float* __restrict__ WoT, const float* __restrict__ bo,
                float* __restrict__ out)
{
    const int tid = threadIdx.x;
    const int w = tid >> 6;          // wave 0..15
    const int h = w & 7;             // head
    const int jh = w >> 3;           // j-half
    const int lane = tid & 63;
    const int r = lane & 15;         // A-frag row / B-frag col
    const int jg = lane >> 4;        // j-octet group
    // XCD-aware bijective swizzle (512 % 8 == 0)
    const int bid = (blockIdx.x & 7) * 64 + (blockIdx.x >> 3);
    const int b = bid >> 7;
    const int tile = bid & 127;
    const int ibase = tile << 4;

    __shared__ float hacc[16][128];
    __shared__ float hsum[8][16];

    const float2 eiq = EI[(b * 8 + h) * 2048 + ibase + r];
    f32x2 EiE;  EiE[0]  = eiq.x; EiE[1]  = eiq.x;   // {exp(ei), exp(ei)}
    f32x2 Ei5E; Ei5E[0] = eiq.y; Ei5E[1] = eiq.y;   // {exp(.2ei), exp(.2ei)}
    const float* EjR  = EjT  + (b * 8 + h) * 2048;
    const float* Ej5R = Ej5T + (b * 8 + h) * 2048;
    const unsigned short* vrow = wxT + ((size_t)(b * 128 + h * 16 + r)) * 2048;
    const unsigned long long* brow = bits + ((size_t)(b * 2048 + ibase + r)) * 32;

    f32x4 acc  = {0.f, 0.f, 0.f, 0.f};
    f32x4 accS = {0.f, 0.f, 0.f, 0.f};
    bf16x8 ones;
    #pragma unroll
    for (int e2 = 0; e2 < 8; ++e2) ones[e2] = (__bf16)1.0f;

    const int jt0 = jh * 1024;
    const int jaof = jg * 8;

    // ---- prologue loads for first jt
    unsigned long long blC = brow[jt0 >> 6];
    float4 eC[4], e5C[4]; bf16x8 vC[2];
    {
        const int j0 = jt0 + jaof, j1 = jt0 + 32 + jaof;
        eC[0]  = *reinterpret_cast<const float4*>(&EjR[j0]);
        eC[1]  = *reinterpret_cast<const float4*>(&EjR[j0 + 4]);
        eC[2]  = *reinterpret_cast<const float4*>(&EjR[j1]);
        eC[3]  = *reinterpret_cast<const float4*>(&EjR[j1 + 4]);
        e5C[0] = *reinterpret_cast<const float4*>(&Ej5R[j0]);
        e5C[1] = *reinterpret_cast<const float4*>(&Ej5R[j0 + 4]);
        e5C[2] = *reinterpret_cast<const float4*>(&Ej5R[j1]);
        e5C[3] = *reinterpret_cast<const float4*>(&Ej5R[j1 + 4]);
        vC[0]  = *reinterpret_cast<const bf16x8*>(&vrow[j0]);
        vC[1]  = *reinterpret_cast<const bf16x8*>(&vrow[j1]);
    }

    #pragma unroll 2
    for (int it = 0; it < 16; ++it) {
        // ---- prefetch next jt (wraps on last iter; result discarded)
        const int itn = (it == 15) ? 0 : (it + 1);
        const int jtn = jt0 + itn * 64;
        const unsigned long long blN = brow[jtn >> 6];
        float4 eN[4], e5N[4]; bf16x8 vN[2];
        const int j0n = jtn + jaof, j1n = jtn + 32 + jaof;
        eN[0]  = *reinterpret_cast<const float4*>(&EjR[j0n]);
        eN[1]  = *reinterpret_cast<const float4*>(&EjR[j0n + 4]);
        eN[2]  = *reinterpret_cast<const float4*>(&EjR[j1n]);
        eN[3]  = *reinterpret_cast<const float4*>(&EjR[j1n + 4]);
        e5N[0] = *reinterpret_cast<const float4*>(&Ej5R[j0n]);
        e5N[1] = *reinterpret_cast<const float4*>(&Ej5R[j0n + 4]);
        e5N[2] = *reinterpret_cast<const float4*>(&Ej5R[j1n]);
        e5N[3] = *reinterpret_cast<const float4*>(&Ej5R[j1n + 4]);
        vN[0]  = *reinterpret_cast<const bf16x8*>(&vrow[j0n]);
        vN[1]  = *reinterpret_cast<const bf16x8*>(&vrow[j1n]);

        // ---- compute current jt
        const unsigned long long bl = blC >> jaof;  // bit (kk*32+e) = mask
        const unsigned int mk[2] = {(unsigned int)bl, (unsigned int)(bl >> 32)};
        #pragma unroll
        for (int kk = 0; kk < 2; ++kk) {
            const unsigned int m = mk[kk];
            bf16x8 afr;
            #pragma unroll
            for (int ep = 0; ep < 4; ++ep) {
                const float4 ejv  = eC [kk * 2 + (ep >> 1)];
                const float4 ej5v = e5C[kk * 2 + (ep >> 1)];
                f32x2 ejp, ej5p;
                if (ep & 1) { ejp[0] = ejv.z;  ejp[1] = ejv.w;
                              ej5p[0] = ej5v.z; ej5p[1] = ej5v.w; }
                else        { ejp[0] = ejv.x;  ejp[1] = ejv.y;
                              ej5p[0] = ej5v.x; ej5p[1] = ej5v.y; }
                const f32x2 t1 = EiE * ejp;     // {Ei*Ej0, Ei*Ej1}
                const f32x2 t2 = Ei5E * ej5p;   // {Ei5*Ej50, Ei5*Ej51}
#if __has_builtin(__builtin_elementwise_max)
                const f32x2 tm = __builtin_elementwise_max(t1, t2);
#else
                f32x2 tm; tm[0] = fmaxf(t1[0], t2[0]); tm[1] = fmaxf(t1[1], t2[1]);
#endif
                afr[2 * ep]     = (__bf16)(((m >> (2 * ep)) & 1u)     ? tm[0] : 0.f);
                afr[2 * ep + 1] = (__bf16)(((m >> (2 * ep + 1)) & 1u) ? tm[1] : 0.f);
            }
            acc  = __builtin_amdgcn_mfma_f32_16x16x32_bf16(afr, vC[kk], acc,  0, 0, 0);
            accS = __builtin_amdgcn_mfma_f32_16x16x32_bf16(afr, ones,   accS, 0, 0, 0);
        }

        blC = blN;
        #pragma unroll
        for (int k2 = 0; k2 < 4; ++k2) { eC[k2] = eN[k2]; e5C[k2] = e5N[k2]; }
        vC[0] = vN[0]; vC[1] = vN[1];
    }

    // C/D layout: col = lane&15, row = (lane>>4)*4 + q. accS[q] = partial row sum.
    if (jh == 1) {
        #pragma unroll
        for (int q = 0; q < 4; ++q)
            hacc[jg * 4 + q][h * 16 + r] = acc[q];
        if (r == 0) {
            #pragma unroll
            for (int q = 0; q < 4; ++q) hsum[h][jg * 4 + q] = accS[q];
        }
    }
    __syncthreads();
    if (jh == 0) {
        #pragma unroll
        for (int q = 0; q < 4; ++q) {
            const int row = jg * 4 + q;
            const float num = acc[q] + hacc[row][h * 16 + r];
            const float den = accS[q] + hsum[h][row];
            const float inv = (den > 0.f) ? 1.f / den : 0.f;  // empty row -> 0
            hacc[row][h * 16 + r] = num * inv;
        }
    }
    __syncthreads();

    // ---- fused out-proj + ELU: 1024 threads, 2 rows each
    const int f = tid & 127;
    const int rg = tid >> 7;  // 8 groups x 2 rows
    float o0 = 0.f, o1 = 0.f;
    for (int k = 0; k < 128; k += 4) {
        const float w0 = WoT[(k + 0) * 128 + f];
        const float w1 = WoT[(k + 1) * 128 + f];
        const float w2 = WoT[(k + 2) * 128 + f];
        const float w3 = WoT[(k + 3) * 128 + f];
        const float4 h0 = *reinterpret_cast<const float4*>(&hacc[rg * 2 + 0][k]);
        const float4 h1 = *reinterpret_cast<const float4*>(&hacc[rg * 2 + 1][k]);
        o0 += h0.x * w0 + h0.y * w1 + h0.z * w2 + h0.w * w3;
        o1 += h1.x * w0 + h1.y * w1 + h1.z * w2 + h1.w * w3;
    }
    const float bv = bo[f];
    float vv[2] = {o0 + bv, o1 + bv};
    #pragma unroll
    for (int q = 0; q < 2; ++q) {
        float v = vv[q];
        v = (v > 0.f) ? v : (__expf(v) - 1.f);
        out[(size_t)(b * 2048 + ibase + rg * 2 + q) * 128 + f] = v;
    }
}

extern "C" void kernel_launch(void* const* d_in, const int* in_sizes, int n_in,
                              void* d_out, int out_size, void* d_ws, size_t ws_size,
                              hipStream_t stream) {
    const float* x   = (const float*)d_in[0];
    const int*   adj = (const int*)d_in[1];
    const float* W   = (const float*)d_in[2];
    const float* a   = (const float*)d_in[3];
    const float* Wo  = (const float*)d_in[4];
    const float* bo  = (const float*)d_in[5];
    float* out = (float*)d_out;

    // ws: wxT 2MB | EI 512K | EjT 256K | Ej5T 256K | WoT 64K | bits 2MB
    char* ws = (char*)d_ws;
    unsigned short* wxT = (unsigned short*)ws;
    float2* EI  = (float2*)(ws + (size_t)2 * 1024 * 1024);
    float* EjT  = (float*)(EI + 4 * 8 * 2048);
    float* Ej5T = EjT + 4 * 8 * 2048;
    float* WoT  = Ej5T + 4 * 8 * 2048;
    unsigned long long* bits = (unsigned long long*)(WoT + 128 * 128);

    prep_kernel<<<dim3(1025 + 2048), dim3(256), 0, stream>>>(
        x, W, a, Wo, adj, wxT, EI, EjT, Ej5T, WoT, bits);
    gat_kernel<<<dim3(512), dim3(1024), 0, stream>>>(
        bits, wxT, EI, EjT, Ej5T, WoT, bo, out);
}

// Round 9
// 86.072 us; speedup vs baseline: 1.2751x; 1.2751x over previous
//
#include <hip/hip_runtime.h>
#include <hip/hip_bf16.h>
#include <cstdint>

// GAT fused layer: B=4, N=2048, F=128, H=8, HD=16, all fp32 I/O.
// Identity: exp(leaky(si+sj)) = max(exp(si)exp(sj), exp(.2si)exp(.2sj))
// Masks: row-major coalesced pack (r8-proven) + separate transpose kernel ->
//   wave-uniform u64 words; in gat loaded via compiler-scalarized uniform
//   loads and applied with inverse_ballot (1 VALU per 64 scores).
// gat: 512-thr / 8 waves (1 per head), 32 rows (2 i-tiles) per block, full
//   j-range, static-parity A/B register double-buffer, aggregation + row-sum
//   via mfma_f32_16x16x32_bf16 (B=ones), fused out-proj + ELU.

typedef float f32x2 __attribute__((ext_vector_type(2)));
typedef float f32x4 __attribute__((ext_vector_type(4)));
typedef __bf16 bf16x8 __attribute__((ext_vector_type(8)));

__device__ __forceinline__ float lsel(float v, unsigned long long m,
                                      unsigned long long lanebit) {
#if __has_builtin(__builtin_amdgcn_inverse_ballot_w64)
    (void)lanebit;
    return __builtin_amdgcn_inverse_ballot_w64(m) ? v : 0.0f;
#else
    return (m & lanebit) ? v : 0.0f;
#endif
}

__device__ __forceinline__ void tile_step(
    f32x4& acc, f32x4& accS, f32x2 EiE, f32x2 Ei5E,
    const unsigned long long* __restrict__ tmw, unsigned long long lanebit,
    float4 e0, float4 e1, float4 f0, float4 f1, bf16x8 vk, bf16x8 ones)
{
    bf16x8 afr;
    #pragma unroll
    for (int ep = 0; ep < 4; ++ep) {
        const float4 ejv = (ep & 2) ? e1 : e0;
        const float4 ej5 = (ep & 2) ? f1 : f0;
        f32x2 ejp, ej5p;
        if (ep & 1) { ejp[0]=ejv.z; ejp[1]=ejv.w; ej5p[0]=ej5.z; ej5p[1]=ej5.w; }
        else        { ejp[0]=ejv.x; ejp[1]=ejv.y; ej5p[0]=ej5.x; ej5p[1]=ej5.y; }
        const f32x2 t1 = EiE * ejp;          // {Ei*Ej0, Ei*Ej1}
        const f32x2 t2 = Ei5E * ej5p;        // {Ei5*Ej50, Ei5*Ej51}
#if __has_builtin(__builtin_elementwise_max)
        const f32x2 tm = __builtin_elementwise_max(t1, t2);
#else
        f32x2 tm; tm[0] = fmaxf(t1[0], t2[0]); tm[1] = fmaxf(t1[1], t2[1]);
#endif
        afr[2*ep]   = (__bf16)lsel(tm[0], tmw[2*ep],   lanebit);
        afr[2*ep+1] = (__bf16)lsel(tm[1], tmw[2*ep+1], lanebit);
    }
    acc  = __builtin_amdgcn_mfma_f32_16x16x32_bf16(afr, vk,   acc,  0, 0, 0);
    accS = __builtin_amdgcn_mfma_f32_16x16x32_bf16(afr, ones, accS, 0, 0, 0);
}

__global__ __launch_bounds__(256)
void prep_kernel(const float* __restrict__ x, const float* __restrict__ W,
                 const float* __restrict__ a, const float* __restrict__ Wo,
                 const int* __restrict__ adj,
                 unsigned short* __restrict__ wxT,
                 float2* __restrict__ EI,
                 float* __restrict__ EjT, float* __restrict__ Ej5T,
                 float* __restrict__ WoT,
                 unsigned long long* __restrict__ bits)
{
    const int t = threadIdx.x;

    if (blockIdx.x >= 1025) {
        // ---- row-major pack: 2048 blocks x 4 rows (proven)
        const int wid = (blockIdx.x - 1025) * 4 + (t >> 6);  // row 0..8191
        const int lane = t & 63;
        const int* row = adj + (size_t)wid * 2048;
        unsigned long long* brow = bits + (size_t)wid * 32;
        #pragma unroll 2
        for (int it = 0; it < 8; ++it) {
            const int base = it * 256;
            const unsigned long long w0 = __ballot(row[base + lane] != 0);
            const unsigned long long w1 = __ballot(row[base + 64 + lane] != 0);
            const unsigned long long w2 = __ballot(row[base + 128 + lane] != 0);
            const unsigned long long w3 = __ballot(row[base + 192 + lane] != 0);
            if (lane == 0) {
                ulonglong2 p0; p0.x = w0; p0.y = w1;
                ulonglong2 p1; p1.x = w2; p1.y = w3;
                *reinterpret_cast<ulonglong2*>(&brow[it * 4])     = p0;
                *reinterpret_cast<ulonglong2*>(&brow[it * 4 + 2]) = p1;
            }
        }
        return;
    }

    // ---- proj: blocks 0..1024 (t<128 active)
    const int blk = blockIdx.x;
    if (blk == 1024) {
        if (t < 128)
            for (int k = 0; k < 128; ++k)
                WoT[k * 128 + t] = Wo[t * 128 + k];
        return;
    }
    __shared__ float xl[8 * 128];
    __shared__ float xw[8 * 128];
    const int row0 = blk * 8;
    if (t < 128) {
        #pragma unroll
        for (int r = 0; r < 8; ++r)
            xl[r * 128 + t] = x[(size_t)(row0 + r) * 128 + t];
    }
    __syncthreads();

    if (t < 128) {
        float acc[8] = {0.f, 0.f, 0.f, 0.f, 0.f, 0.f, 0.f, 0.f};
        for (int k = 0; k < 128; k += 4) {
            const float w0 = W[(k + 0) * 128 + t];
            const float w1 = W[(k + 1) * 128 + t];
            const float w2 = W[(k + 2) * 128 + t];
            const float w3 = W[(k + 3) * 128 + t];
            #pragma unroll
            for (int r = 0; r < 8; ++r) {
                const float4 xv = *reinterpret_cast<const float4*>(&xl[r * 128 + k]);
                acc[r] += xv.x * w0 + xv.y * w1 + xv.z * w2 + xv.w * w3;
            }
        }
        #pragma unroll
        for (int r = 0; r < 8; ++r) xw[r * 128 + t] = acc[r];
    }
    __syncthreads();

    if (t < 128) {
        const int b = row0 >> 11, n0 = row0 & 2047;
        bf16x8 st;
        #pragma unroll
        for (int r = 0; r < 8; ++r) st[r] = (__bf16)xw[r * 128 + t];
        *reinterpret_cast<bf16x8*>(&wxT[((size_t)(b * 128 + t)) * 2048 + n0]) = st;

        const int r = t >> 4, h = (t >> 1) & 7, s = t & 1;
        float dot = 0.f;
        #pragma unroll
        for (int d = 0; d < 16; ++d)
            dot += xw[r * 128 + h * 16 + d] * a[h * 32 + s * 16 + d];
        const float ef  = __expf(dot);
        const float ef5 = __expf(0.2f * dot);
        const int idx = (b * 8 + h) * 2048 + n0 + r;
        if (s) { EjT[idx] = ef; Ej5T[idx] = ef5; }
        else   { float2 ev; ev.x = ef; ev.y = ef5; EI[idx] = ev; }
    }
}

// bits [8192][32] (bit j-off per row)  ->  tmask [(b*128+tile)*32+jtw][16]
// word(kk,e) bit l = adj[tile*16+(l&15)][jtw*64 + kk*32 + (l>>4)*8 + e]
__global__ __launch_bounds__(256)
void tpose_kernel(const unsigned long long* __restrict__ bits,
                  unsigned long long* __restrict__ tmask)
{
    const int lane = threadIdx.x & 63;
    const int wgid = blockIdx.x * 4 + (threadIdx.x >> 6);  // 0..1023
    const int rsel = lane & 15;
    const int shb  = (lane >> 4) * 8;
    for (int i = 0; i < 16; ++i) {
        const int task = wgid * 16 + i;        // 0..16383 = (b, tile, jtw)
        const int b = task >> 12;
        const int tile = (task >> 5) & 127;
        const int jtw = task & 31;
        const unsigned long long mw =
            bits[((size_t)(b * 2048 + tile * 16 + rsel)) * 32 + jtw];
        unsigned long long w[16];
        #pragma unroll
        for (int kk = 0; kk < 2; ++kk)
            #pragma unroll
            for (int e = 0; e < 8; ++e)
                w[kk * 8 + e] = __ballot(((mw >> (kk * 32 + shb + e)) & 1ull) != 0);
        if (lane == 0) {
            unsigned long long* dst =
                tmask + ((size_t)((b * 128 + tile) * 32 + jtw)) * 16;
            #pragma unroll
            for (int q2 = 0; q2 < 8; ++q2) {
                ulonglong2 p; p.x = w[2 * q2]; p.y = w[2 * q2 + 1];
                *reinterpret_cast<ulonglong2*>(&dst[2 * q2]) = p;
            }
        }
    }
}

#define LOADJ(S, JT) do {                                                   \
    const int j0_ = (JT) + jaof, j1_ = (JT) + 32 + jaof;                    \
    e##S##0 = *reinterpret_cast<const float4*>(&EjR[j0_]);                  \
    e##S##1 = *reinterpret_cast<const float4*>(&EjR[j0_ + 4]);              \
    e##S##2 = *reinterpret_cast<const float4*>(&EjR[j1_]);                  \
    e##S##3 = *reinterpret_cast<const float4*>(&EjR[j1_ + 4]);              \
    f##S##0 = *reinterpret_cast<const float4*>(&Ej5R[j0_]);                 \
    f##S##1 = *reinterpret_cast<const float4*>(&Ej5R[j0_ + 4]);             \
    f##S##2 = *reinterpret_cast<const float4*>(&Ej5R[j1_]);                 \
    f##S##3 = *reinterpret_cast<const float4*>(&Ej5R[j1_ + 4]);             \
    v##S##0 = *reinterpret_cast<const bf16x8*>(&vrow[j0_]);                 \
    v##S##1 = *reinterpret_cast<const bf16x8*>(&vrow[j1_]);                 \
} while (0)

#define STEP(S, JT) do {                                                    \
    const unsigned long long* wA_ = tmA + ((JT) >> 6) * 16;                 \
    const unsigned long long* wB_ = tmB + ((JT) >> 6) * 16;                 \
    tile_step(acc0, accS0, E0, E50, wA_,     lanebit,                       \
              e##S##0, e##S##1, f##S##0, f##S##1, v##S##0, ones);           \
    tile_step(acc0, accS0, E0, E50, wA_ + 8, lanebit,                       \
              e##S##2, e##S##3, f##S##2, f##S##3, v##S##1, ones);           \
    tile_step(acc1, accS1, E1, E51, wB_,     lanebit,                       \
              e##S##0, e##S##1, f##S##0, f##S##1, v##S##0, ones);           \
    tile_step(acc1, accS1, E1, E51, wB_ + 8, lanebit,                       \
              e##S##2, e##S##3, f##S##2, f##S##3, v##S##1, ones);           \
} while (0)

__global__ __launch_bounds__(512, 2)
void gat_kernel(const unsigned long long* __restrict__ tmask,
                const unsigned short* __restrict__ wxT,
                const float2* __restrict__ EI,
                const float* __restrict__ EjT, const float* __restrict__ Ej5T,
                const float* __restrict__ WoT, const float* __restrict__ bo,
                float* __restrict__ out)
{
    const int tid = threadIdx.x;
    const int h = tid >> 6;              // wave = head
    const int lane = tid & 63;
    const int r = lane & 15;             // A-frag row / B-frag col
    const int jg = lane >> 4;
    const int jaof = jg * 8;
    const unsigned long long lanebit = 1ull << lane;
    // XCD-aware bijective swizzle (256 % 8 == 0)
    const int bid = (blockIdx.x & 7) * 32 + (blockIdx.x >> 3);
    const int b = bid >> 6;
    const int tp = bid & 63;             // 32-row mega-tile
    const int ibase = tp << 5;

    __shared__ float hacc[32][128];

    const int eb = (b * 8 + h) * 2048;
    const float2 q0 = EI[eb + ibase + r];
    const float2 q1 = EI[eb + ibase + 16 + r];
    f32x2 E0, E50, E1, E51;
    E0[0] = q0.x;  E0[1] = q0.x;   E50[0] = q0.y;  E50[1] = q0.y;
    E1[0] = q1.x;  E1[1] = q1.x;   E51[0] = q1.y;  E51[1] = q1.y;
    const float* EjR  = EjT  + eb;
    const float* Ej5R = Ej5T + eb;
    const unsigned short* vrow = wxT + ((size_t)(b * 128 + h * 16 + r)) * 2048;
    const unsigned long long* tmA = tmask + ((size_t)(b * 128 + tp * 2)) * 512;
    const unsigned long long* tmB = tmA + 512;

    f32x4 acc0 = {0.f,0.f,0.f,0.f}, accS0 = {0.f,0.f,0.f,0.f};
    f32x4 acc1 = {0.f,0.f,0.f,0.f}, accS1 = {0.f,0.f,0.f,0.f};
    bf16x8 ones;
    #pragma unroll
    for (int e2 = 0; e2 < 8; ++e2) ones[e2] = (__bf16)1.0f;

    float4 eA0, eA1, eA2, eA3, fA0, fA1, fA2, fA3;
    float4 eB0, eB1, eB2, eB3, fB0, fB1, fB2, fB3;
    bf16x8 vA0, vA1, vB0, vB1;

    LOADJ(A, 0);
    for (int jt = 0; jt < 2048; jt += 128) {
        LOADJ(B, jt + 64);
        STEP(A, jt);
        LOADJ(A, (jt + 128) & 2047);   // wraps on last iter (discarded)
        STEP(B, jt + 64);
    }

    // C/D layout: col = lane&15 (=feature r), row = jg*4+q (=node row)
    #pragma unroll
    for (int q = 0; q < 4; ++q) {
        const int row = jg * 4 + q;
        const float i0 = (accS0[q] > 0.f) ? 1.f / accS0[q] : 0.f;
        const float i1 = (accS1[q] > 0.f) ? 1.f / accS1[q] : 0.f;
        hacc[row][h * 16 + r]      = acc0[q] * i0;
        hacc[16 + row][h * 16 + r] = acc1[q] * i1;
    }
    __syncthreads();

    // ---- fused out-proj + ELU: 512 threads x 8 rows
    const int f = tid & 127;
    const int rg = tid >> 7;  // 4 groups x 8 rows
    float o[8] = {0.f, 0.f, 0.f, 0.f, 0.f, 0.f, 0.f, 0.f};
    for (int k = 0; k < 128; k += 4) {
        const float w0 = WoT[(k + 0) * 128 + f];
        const float w1 = WoT[(k + 1) * 128 + f];
        const float w2 = WoT[(k + 2) * 128 + f];
        const float w3 = WoT[(k + 3) * 128 + f];
        #pragma unroll
        for (int q = 0; q < 8; ++q) {
            const float4 hv = *reinterpret_cast<const float4*>(&hacc[rg * 8 + q][k]);
            o[q] += hv.x * w0 + hv.y * w1 + hv.z * w2 + hv.w * w3;
        }
    }
    const float bv = bo[f];
    #pragma unroll
    for (int q = 0; q < 8; ++q) {
        float v = o[q] + bv;
        v = (v > 0.f) ? v : (__expf(v) - 1.f);
        out[(size_t)(b * 2048 + ibase + rg * 8 + q) * 128 + f] = v;
    }
}

extern "C" void kernel_launch(void* const* d_in, const int* in_sizes, int n_in,
                              void* d_out, int out_size, void* d_ws, size_t ws_size,
                              hipStream_t stream) {
    const float* x   = (const float*)d_in[0];
    const int*   adj = (const int*)d_in[1];
    const float* W   = (const float*)d_in[2];
    const float* a   = (const float*)d_in[3];
    const float* Wo  = (const float*)d_in[4];
    const float* bo  = (const float*)d_in[5];
    float* out = (float*)d_out;

    // ws: wxT 2MB | EI 512K | EjT 256K | Ej5T 256K | WoT 64K | bits 2MB | tmask 2MB
    char* ws = (char*)d_ws;
    unsigned short* wxT = (unsigned short*)ws;
    float2* EI  = (float2*)(ws + (size_t)2 * 1024 * 1024);
    float* EjT  = (float*)(EI + 4 * 8 * 2048);
    float* Ej5T = EjT + 4 * 8 * 2048;
    float* WoT  = Ej5T + 4 * 8 * 2048;
    unsigned long long* bits  = (unsigned long long*)(WoT + 128 * 128);
    unsigned long long* tmask = bits + (size_t)8192 * 32;

    prep_kernel<<<dim3(1025 + 2048), dim3(256), 0, stream>>>(
        x, W, a, Wo, adj, wxT, EI, EjT, Ej5T, WoT, bits);
    tpose_kernel<<<dim3(256), dim3(256), 0, stream>>>(bits, tmask);
    gat_kernel<<<dim3(256), dim3(512), 0, stream>>>(
        tmask, wxT, EI, EjT, Ej5T, WoT, bo, out);
}